// Round 12
// baseline (319.077 us; speedup 1.0000x reference)
//
#include <hip/hip_runtime.h>

#define S_LEN 2048
#define B_DIM 32
#define H_DIM 1024
#define ROWS 8       // s-rows per wave (measured optimum)
#define KSPLIT 4
#define KCH (H_DIM / KSPLIT)        // 256
#define NPROJ (B_DIM * KSPLIT)      // 128 producer blocks

typedef float fx4 __attribute__((ext_vector_type(4)));

// ---------------------------------------------------------------------------
// Fused kernel: grid (8, 256) = 2048 blocks x 256 threads (dispatch-linear
// id = y*8+x).
//  - blocks 0..127 (first dispatched): compute one (kp,b) slice of
//    vp[kp,b,:] = partial dec@W, release via device-scope flag.
//  - ALL blocks: issue group-0 enc prefetch (16 float4 in flight -> HBM
//    saturates during proj), spin on flag (load-poll + s_sleep, rocPRIM
//    decoupled-lookback pattern: consumers have higher ids than producers),
//    acquire fence, then the round-4 measured-optimum dot loop.
// Values are timing-independent -> deterministic output. All pointers keep
// __restrict__ (round-10 lesson: losing restrict breaks load batching).
// Bias omitted: constant per softmax row, softmax-invariant.
// ---------------------------------------------------------------------------
__global__ __launch_bounds__(256) void fused_energy_kernel(
    const float* __restrict__ dec, const float* __restrict__ W,
    const float* __restrict__ enc, float* __restrict__ vp,
    float* __restrict__ e, int* __restrict__ flag)
{
    const int tid  = threadIdx.x;
    const int lane = tid & 63;
    const int wv   = tid >> 6;
    const int bid  = blockIdx.y * 8 + blockIdx.x;   // dispatch-linear

    // ---- producer part: vp[kp,b,h] = sum_{k in chunk} dec[b,k] W[k,h]
    if (bid < NPROJ) {
        const int pb = bid >> 2;
        const int kp = bid & 3;
        const int k0 = kp * KCH;
        const float* __restrict__ drow = dec + (size_t)pb * H_DIM;
        const fx4* __restrict__ W4 = reinterpret_cast<const fx4*>(W);

        fx4 pacc = {0.f, 0.f, 0.f, 0.f};
#pragma unroll 8
        for (int kk = 0; kk < KCH; ++kk) {
            const int k = k0 + kk;
            pacc += drow[k] * W4[(size_t)k * (H_DIM / 4) + tid];  // drow -> s_load
        }
        reinterpret_cast<fx4*>(vp + ((size_t)kp * B_DIM + pb) * H_DIM)[tid] = pacc;
        __threadfence();                 // flush this thread's vp stores
        __syncthreads();                 // whole slice flushed
        if (tid == 0) atomicAdd(flag, 1);  // device-scope release
    }

    // ---- energy part (all blocks)
    const int b  = blockIdx.x * 4 + wv;
    const int s0 = blockIdx.y * ROWS;

    // group-0 enc prefetch: 16 independent float4 loads in flight BEFORE the
    // spin -- the enc stream runs while producers compute.
    fx4 a[4][4];
#pragma unroll
    for (int r = 0; r < 4; ++r) {
        const fx4* __restrict__ ep = reinterpret_cast<const fx4*>(
            enc + ((size_t)(s0 + r) * B_DIM + b) * H_DIM);
#pragma unroll
        for (int i = 0; i < 4; ++i)
            a[r][i] = ep[lane + 64 * i];
    }
    asm volatile("" ::: "memory");       // pin prefetch issue before the spin

    if (tid == 0) {
        while (__hip_atomic_load(flag, __ATOMIC_RELAXED,
                                 __HIP_MEMORY_SCOPE_AGENT) < NPROJ)
            __builtin_amdgcn_s_sleep(8); // load-poll + backoff: no RMW storm
    }
    __syncthreads();
    __threadfence();                     // acquire: invalidate stale vp lines

    // v[b,:] fragment = sum of 4 partials (L2-resident)
    fx4 vf[4];
#pragma unroll
    for (int i = 0; i < 4; ++i) {
        fx4 t = {0.f, 0.f, 0.f, 0.f};
#pragma unroll
        for (int kp = 0; kp < KSPLIT; ++kp) {
            const fx4* __restrict__ p = reinterpret_cast<const fx4*>(
                vp + ((size_t)kp * B_DIM + b) * H_DIM);
            t += p[lane + 64 * i];
        }
        vf[i] = t;
    }

    float acc[ROWS];
    // group 0: consume prefetched a[][]
#pragma unroll
    for (int r = 0; r < 4; ++r) {
        float t = 0.f;
#pragma unroll
        for (int i = 0; i < 4; ++i)
            t += a[r][i].x * vf[i].x + a[r][i].y * vf[i].y +
                 a[r][i].z * vf[i].z + a[r][i].w * vf[i].w;
        acc[r] = t;
    }
    // group 1: load + consume (round-4 pattern)
#pragma unroll
    for (int r = 0; r < 4; ++r) {
        const fx4* __restrict__ ep = reinterpret_cast<const fx4*>(
            enc + ((size_t)(s0 + 4 + r) * B_DIM + b) * H_DIM);
#pragma unroll
        for (int i = 0; i < 4; ++i)
            a[r][i] = ep[lane + 64 * i];
    }
#pragma unroll
    for (int r = 0; r < 4; ++r) {
        float t = 0.f;
#pragma unroll
        for (int i = 0; i < 4; ++i)
            t += a[r][i].x * vf[i].x + a[r][i].y * vf[i].y +
                 a[r][i].z * vf[i].z + a[r][i].w * vf[i].w;
        acc[4 + r] = t;
    }

#pragma unroll
    for (int off = 32; off; off >>= 1) {
#pragma unroll
        for (int r = 0; r < ROWS; ++r)
            acc[r] += __shfl_xor(acc[r], off, 64);
    }

    if (lane == 0) {
        fx4 o0, o1;
        o0.x = acc[0]; o0.y = acc[1]; o0.z = acc[2]; o0.w = acc[3];
        o1.x = acc[4]; o1.y = acc[5]; o1.z = acc[6]; o1.w = acc[7];
        fx4* ep = reinterpret_cast<fx4*>(e + (size_t)b * S_LEN + s0);
        ep[0] = o0;
        ep[1] = o1;
    }
}

// ---------------------------------------------------------------------------
// Softmax: out[b,0,s] = softmax_s(e[b,s]). One block per b.
// ---------------------------------------------------------------------------
__global__ __launch_bounds__(256) void softmax_kernel(
    const float* __restrict__ e, float* __restrict__ out)
{
    __shared__ float red[4];
    const int b    = blockIdx.x;
    const int tid  = threadIdx.x;
    const int lane = tid & 63;
    const int wv   = tid >> 6;
    const float* __restrict__ row = e + (size_t)b * S_LEN;

    float vals[8];
    float m = -1e30f;
#pragma unroll
    for (int i = 0; i < 8; ++i) {
        vals[i] = row[tid + 256 * i];
        m = fmaxf(m, vals[i]);
    }
#pragma unroll
    for (int off = 32; off; off >>= 1)
        m = fmaxf(m, __shfl_xor(m, off, 64));
    if (lane == 0) red[wv] = m;
    __syncthreads();
    m = fmaxf(fmaxf(red[0], red[1]), fmaxf(red[2], red[3]));

    float sum = 0.0f;
#pragma unroll
    for (int i = 0; i < 8; ++i) {
        vals[i] = __expf(vals[i] - m);
        sum += vals[i];
    }
#pragma unroll
    for (int off = 32; off; off >>= 1)
        sum += __shfl_xor(sum, off, 64);
    __syncthreads();                 // red reuse hazard
    if (lane == 0) red[wv] = sum;
    __syncthreads();
    sum = red[0] + red[1] + red[2] + red[3];

    const float inv = 1.0f / sum;
#pragma unroll
    for (int i = 0; i < 8; ++i)
        out[(size_t)b * S_LEN + tid + 256 * i] = vals[i] * inv;
}

// ---------------------------------------------------------------------------
extern "C" void kernel_launch(void* const* d_in, const int* in_sizes, int n_in,
                              void* d_out, int out_size, void* d_ws, size_t ws_size,
                              hipStream_t stream)
{
    const float* dec = (const float*)d_in[0];   // [B,H]
    const float* enc = (const float*)d_in[1];   // [S,B,H]
    const float* W   = (const float*)d_in[2];   // [H,H]
    // d_in[3] = bias: constant-per-row contribution, softmax-invariant -> unused
    float* out = (float*)d_out;                 // [B,1,S] flat

    float* vp   = (float*)d_ws;                 // KSPLIT*B*H floats (512 KiB)
    float* e    = vp + KSPLIT * B_DIM * H_DIM;  // B*S floats        (256 KiB)
    int*   flag = (int*)(e + B_DIM * S_LEN);    // 1 int (ws is poisoned 0xAA)

    hipMemsetAsync(flag, 0, sizeof(int), stream);
    fused_energy_kernel<<<dim3(B_DIM / 4, S_LEN / ROWS), 256, 0, stream>>>(
        dec, W, enc, vp, e, flag);
    softmax_kernel<<<B_DIM, 256, 0, stream>>>(e, out);
}